// Round 3
// baseline (320.937 us; speedup 1.0000x reference)
//
#include <hip/hip_runtime.h>
#include <math.h>

#define NB_B 65536
#define NL   512
#define NP   96
#define NE   16
#define NEL  14
#define NF   256
#define TEMP_INV (1.0f/0.07f)
#define TAU  1e-5f
#define PI_D 3.14159265358979323846
#define MAXCHK 1280

typedef __attribute__((ext_vector_type(8))) short bf16x8;
typedef __attribute__((ext_vector_type(4))) float f32x4;

// ---------------- workspace layout (bytes) ----------------
// (see defines; xb16 optional at tail)
// K-PERMUTATION: when xb16 is active, both xb16 rows and Wrb rows store the
// 512 K-elements in permuted order slot s = l*8+k  <->  orig = (s&7)*64+(s>>3).
// Dot products over K are permutation-invariant, so k_gemm is unchanged.

#define WS_PCNT     0
#define WS_PTK      16384
#define WS_PBASE    32768
#define WS_FLAGCNT  33792
#define WS_NCHK     33824
#define WS_FLAG     33856
#define WS_SSUM     296000
#define WS_WGT      301376
#define WS_BGT      317760
#define WS_TWF      317824
#define WS_TWD      319872
#define WS_REC      328064
#define WS_HDR      590208
#define WS_RIDX     1638784
#define WS_WRB      1900928
#define WS_DESC     3473792
#define WS_XB16     3480064

__device__ __forceinline__ unsigned short f2bf(float f) {
    unsigned u = __float_as_uint(f);
    unsigned r = (u + 0x7fffu + ((u >> 16) & 1u)) >> 16;
    return (unsigned short)r;
}

// prep + Wr f32->bf16 cvt merged. 768 blocks. perm=1: K-permuted Wrb layout.
__global__ __launch_bounds__(256) void k_prep(
    const float* __restrict__ Wg, const float* __restrict__ bg,
    const float* __restrict__ Wr,
    float* __restrict__ Ssum, float* __restrict__ WgE, float* __restrict__ bgT,
    float2* __restrict__ twf, double2* __restrict__ twd,
    int* __restrict__ pcnt, int* __restrict__ flagcnt,
    ushort4* __restrict__ Wrb, int perm)
{
    int g = blockIdx.x * 256 + threadIdx.x;
    {
        ushort4 o = make_ushort4(0, 0, 0, 0);
        if (g < NEL * NP * NL / 4) {
            float4 v;
            if (perm) {
                // output slots 4sq..4sq+3 of row; slot s -> orig (s&7)*64+(s>>3)
                int row = g >> 7, sq = g & 127;
                int ll = sq >> 1, kb = (sq & 1) * 4;
                const float* wr = Wr + (size_t)row * NL + ll;
                v.x = wr[(kb + 0) * 64]; v.y = wr[(kb + 1) * 64];
                v.z = wr[(kb + 2) * 64]; v.w = wr[(kb + 3) * 64];
            } else {
                v = ((const float4*)Wr)[g];
            }
            o.x = f2bf(v.x); o.y = f2bf(v.y); o.z = f2bf(v.z); o.w = f2bf(v.w);
        }
        Wrb[g] = o;
    }
    if (g < NEL * NP) {
        const float4* w = (const float4*)(Wr + (size_t)g * NL);
        float s = 0.f;
        for (int i = 0; i < NL / 4; i++) { float4 v = w[i]; s += v.x + v.y + v.z + v.w; }
        Ssum[g] = s;
    }
    if (g < 4096) {
        int c = g & 3, e = (g >> 2) & 15, f4 = g >> 6;
        WgE[g] = Wg[e * NF + f4 * 4 + c] * TEMP_INV;
    }
    if (g < NF) {
        double a = -2.0 * PI_D * (double)g / 512.0;
        twf[g] = make_float2((float)cos(a), (float)sin(a));
    }
    if (g < 512) {
        double a = -2.0 * PI_D * (double)g / 512.0;
        twd[g] = make_double2(cos(a), sin(a));
    }
    if (g < 256) pcnt[g << 4] = 0;
    if (g < NE) bgT[g] = bg[g] * TEMP_INV;
    if (g == 300) *flagcnt = 0;
}

// Pack-2 real FFT per wave. ALL twiddles in registers (no LDS twiddle table,
// no __syncthreads at all). xb16 emitted as 2 coalesced b128 stores per lane
// in the K-permuted layout (slot l*8+k).
__global__ __launch_bounds__(256) void k_gate(
    const float* __restrict__ x,
    const float4* __restrict__ WgE4, const float* __restrict__ bgT,
    const float2* __restrict__ twf,
    int* __restrict__ rec, float4* __restrict__ hdr,
    int* __restrict__ flaglist, int* __restrict__ flagcnt,
    int* __restrict__ pcnt, unsigned short* __restrict__ xb16)
{
    __shared__ __align__(16) float2 s_z[4][576];
    float* s_Iv = (float*)&s_z[0][0];

    const int t = threadIdx.x;
    const int wv = t >> 6, l = t & 63;
    const int b0 = blockIdx.x * 8 + wv * 2;

    // register twiddles (per-lane, loop-invariant)
    float2 tw0[4], tw1[2];
#pragma unroll
    for (int k = 0; k < 4; k++) tw0[k] = twf[k * 64 + l];
    tw1[0] = twf[2 * l];
    tw1[1] = twf[128 + 2 * l];
    const float2 w2 = twf[l << 2];
    float2 wst[5];
    wst[0] = twf[(l & 31) << 3];
    wst[1] = twf[(l & 15) << 4];
    wst[2] = twf[(l & 7) << 5];
    wst[3] = twf[(l & 3) << 6];
    wst[4] = twf[(l & 1) << 7];

    const float* xa = x + (size_t)b0 * NL;
    const float* xb = xa + NL;
    float xr[8], xi[8];
#pragma unroll
    for (int k = 0; k < 8; k++) { xr[k] = xa[k * 64 + l]; xi[k] = xb[k * 64 + l]; }
    const float last_a = __shfl(xr[7], 63);
    const float last_b = __shfl(xi[7], 63);

    if (xb16) {   // K-permuted bf16 copy: lane stores its 8 values contiguously
        unsigned short ta[8], tb[8];
#pragma unroll
        for (int k = 0; k < 8; k++) { ta[k] = f2bf(xr[k]); tb[k] = f2bf(xi[k]); }
        *(bf16x8*)(xb16 + (size_t)b0 * NL + l * 8)       = *(bf16x8*)ta;
        *(bf16x8*)(xb16 + (size_t)(b0 + 1) * NL + l * 8) = *(bf16x8*)tb;
    }

    // ---- DIF FFT (complex), natural in, bit-reversed out ----
#pragma unroll
    for (int k = 0; k < 4; k++) {                       // stage 0: half=256
        float2 w = tw0[k];
        float ur = xr[k], ui = xi[k], vr = xr[k + 4], vi = xi[k + 4];
        xr[k] = ur + vr; xi[k] = ui + vi;
        float dr = ur - vr, di = ui - vi;
        xr[k + 4] = dr * w.x - di * w.y; xi[k + 4] = dr * w.y + di * w.x;
    }
    {                                                   // stage 1: half=128
        const int kk[4] = {0, 1, 4, 5};
#pragma unroll
        for (int g2 = 0; g2 < 4; g2++) {
            int k = kk[g2];
            float2 w = tw1[k & 1];
            float ur = xr[k], ui = xi[k], vr = xr[k + 2], vi = xi[k + 2];
            xr[k] = ur + vr; xi[k] = ui + vi;
            float dr = ur - vr, di = ui - vi;
            xr[k + 2] = dr * w.x - di * w.y; xi[k + 2] = dr * w.y + di * w.x;
        }
    }
    {                                                   // stage 2: half=64
#pragma unroll
        for (int k = 0; k < 8; k += 2) {
            float ur = xr[k], ui = xi[k], vr = xr[k + 1], vi = xi[k + 1];
            xr[k] = ur + vr; xi[k] = ui + vi;
            float dr = ur - vr, di = ui - vi;
            xr[k + 1] = dr * w2.x - di * w2.y; xi[k + 1] = dr * w2.y + di * w2.x;
        }
    }
#pragma unroll
    for (int st = 3; st < 8; st++) {                    // stages 3..7 cross-lane
        const int half = 256 >> st;
        const float2 w = wst[st - 3];
        const bool up = (l & half) != 0;
        const float sg = up ? -1.f : 1.f;
        const float cc = up ? w.x : 1.f;
        const float ss = up ? w.y : 0.f;
#pragma unroll
        for (int k = 0; k < 8; k++) {
            float pr = __shfl_xor(xr[k], half);
            float pi = __shfl_xor(xi[k], half);
            float tr = fmaf(sg, xr[k], pr);
            float ti = fmaf(sg, xi[k], pi);
            xr[k] = tr * cc - ti * ss;
            xi[k] = tr * ss + ti * cc;
        }
    }
    {                                                   // stage 8: half=1, w=(1,0)
        const float sg = (l & 1) ? -1.f : 1.f;
#pragma unroll
        for (int k = 0; k < 8; k++) {
            float pr = __shfl_xor(xr[k], 1);
            float pi = __shfl_xor(xi[k], 1);
            xr[k] = fmaf(sg, xr[k], pr);
            xi[k] = fmaf(sg, xi[k], pi);
        }
    }

#pragma unroll
    for (int k = 0; k < 8; k++) {
        int i = k * 64 + l;
        s_z[wv][i + (i >> 3)] = make_float2(xr[k], xi[k]);
    }
    // s_z[wv] is wave-private: no barrier needed.

    // conjugate-symmetry split: lane l owns bins f = 4l..4l+3
    float Ia[4], Ib[4];
    float psa = 0.f, psb = 0.f;
#pragma unroll
    for (int j = 0; j < 4; j++) {
        int f = (l << 2) | j;
        int i1_ = (int)(__brev((unsigned)f) >> 23);
        int i2_ = (int)(__brev((unsigned)((512 - f) & 511)) >> 23);
        float2 z1 = s_z[wv][i1_ + (i1_ >> 3)];
        float2 z2 = s_z[wv][i2_ + (i2_ >> 3)];
        float pr_ = z1.x + z2.x, qm = z1.y - z2.y;
        float qp = z1.y + z2.y, pm = z1.x - z2.x;
        float va = pr_ * pr_ + qm * qm;
        float vb = qp * qp + pm * pm;
        if (f == 0) { va = 0.f; vb = 0.f; }   // centering only affects bin 0
        Ia[j] = va; Ib[j] = vb;
        psa += va; psb += vb;
    }
#pragma unroll
    for (int m = 1; m < 64; m <<= 1) {
        psa += __shfl_xor(psa, m); psb += __shfl_xor(psb, m);
    }
    const float psa_raw = psa, psb_raw = psb;
    if (psa == 0.f) psa = 1.f;
    if (psb == 0.f) psb = 1.f;
    const float inv_a = 1.f / psa, inv_b = 1.f / psb;

    const float2 Z0   = s_z[wv][0];
    const float2 Z256 = s_z[wv][1];

    float* wI = s_Iv + wv * 1152;
    const int io = (l << 2) + ((l >> 4) << 2);
    *(float4*)(wI + io)       = make_float4(Ia[0], Ia[1], Ia[2], Ia[3]);
    *(float4*)(wI + 272 + io) = make_float4(Ib[0], Ib[1], Ib[2], Ib[3]);

    // gate matmul: lane (e = l&15, cq = l>>4) sums quarter cq for expert e
    const int e16 = l & 15, cq = l >> 4;
    const float bgv = bgT[e16];
    float accA = 0.f, accB = 0.f;
    const float* rA = wI + cq * 68;
    const float* rB = rA + 272;
#pragma unroll 4
    for (int jj = 0; jj < 16; jj++) {
        float4 ia = *(const float4*)(rA + 4 * jj);
        float4 ib = *(const float4*)(rB + 4 * jj);
        float4 w = WgE4[(cq * 16 + jj) * 16 + e16];
        accA += ia.x * w.x + ia.y * w.y + ia.z * w.z + ia.w * w.w;
        accB += ib.x * w.x + ib.y * w.y + ib.z * w.z + ib.w * w.w;
    }
    accA += __shfl_xor(accA, 16); accA += __shfl_xor(accA, 32);
    accB += __shfl_xor(accB, 16); accB += __shfl_xor(accB, 32);

    float v = ((l & 16) ? accB * inv_b : accA * inv_a) + bgv;

    // parallel top-3 within 16-lane group, first-index tie-break
    float b0v = v; int b0i = e16;
#pragma unroll
    for (int m = 1; m < 16; m <<= 1) {
        float ov = __shfl_xor(b0v, m); int oi = __shfl_xor(b0i, m);
        if (ov > b0v || (ov == b0v && oi < b0i)) { b0v = ov; b0i = oi; }
    }
    float v1 = (e16 == b0i) ? -1e30f : v;
    float b1v = v1; int b1i = e16;
#pragma unroll
    for (int m = 1; m < 16; m <<= 1) {
        float ov = __shfl_xor(b1v, m); int oi = __shfl_xor(b1i, m);
        if (ov > b1v || (ov == b1v && oi < b1i)) { b1v = ov; b1i = oi; }
    }
    float v2 = (e16 == b1i) ? -1e30f : v1;
    float b2v = v2;
#pragma unroll
    for (int m = 1; m < 16; m <<= 1) {
        float ov = __shfl_xor(b2v, m);
        b2v = fmaxf(b2v, ov);
    }

    if (l == 0 || l == 16) {
        const int r = l >> 4;
        const int b = b0 + r;
        const float mu = (r ? Z0.y : Z0.x) * (1.f / 512.f);
        const float Jv = r ? Z256.y : Z256.x;
        const float ps = r ? psb_raw : psa_raw;
        const float sd = sqrtf((0.5f * ps + Jv * Jv) * (1.f / 262144.f) + 1e-5f);
        const float last = r ? last_b : last_a;
        const float w0 = 1.f / (1.f + expf(b1v - b0v));
        const int pid = b0i * 16 + b1i;
        rec[b] = pid;
        hdr[b] = make_float4(mu, sd, last, w0);
        atomicAdd(&pcnt[pid << 4], 1);
        if (b1v - b2v < TAU) {
            int pos = atomicAdd(flagcnt, 1);
            flaglist[pos] = b;
        }
    }
}

// f64 phasor-DFT refinement for flagged rows; fixes pair counts on reclass.
__global__ __launch_bounds__(256) void k_refine(
    const float* __restrict__ x, const double2* __restrict__ twd,
    const float* __restrict__ Wg, const float* __restrict__ bg,
    int* __restrict__ rec, float4* __restrict__ hdr,
    const int* __restrict__ flaglist, const int* __restrict__ flagcnt,
    int* __restrict__ pcnt)
{
    __shared__ double s_x[512];
    __shared__ double s_I[256];
    __shared__ double s_red[16];
    __shared__ double s_g[16];
    const int nf = *flagcnt;
    const int t = threadIdx.x;
    const int wid = t >> 6, lane = t & 63;
    for (int fi = blockIdx.x; fi < nf; fi += gridDim.x) {
        const int b = flaglist[fi];
        const float* xp = x + (size_t)b * NL;
        double v0 = (double)xp[t], v1 = (double)xp[t + 256];
        double lsum = v0 + v1;
        for (int m = 1; m < 64; m <<= 1) lsum += __shfl_xor(lsum, m);
        if (lane == 0) s_red[wid] = lsum;
        __syncthreads();
        double mu = (s_red[0] + s_red[1] + s_red[2] + s_red[3]) * (1.0 / 512.0);
        s_x[t] = v0 - mu; s_x[t + 256] = v1 - mu;
        __syncthreads();
        double2 w = twd[t];
        double pr = 1.0, pi = 0.0, cr = 0.0, ci = 0.0;
        for (int n = 0; n < 512; n++) {
            double xv = s_x[n];
            cr += xv * pr; ci += xv * pi;
            double t2 = pr * w.x - pi * w.y;
            pi = pr * w.y + pi * w.x;
            pr = t2;
        }
        double I = cr * cr + ci * ci;
        s_I[t] = I;
        double ls = I;
        for (int m = 1; m < 64; m <<= 1) ls += __shfl_xor(ls, m);
        if (lane == 0) s_red[8 + wid] = ls;
        __syncthreads();
        double stot = s_red[8] + s_red[9] + s_red[10] + s_red[11];
        if (stot == 0.0) stot = 1.0;
        if (t < 16) {
            double acc = 0.0;
            const float* wrow = Wg + t * NF;
            for (int f = 0; f < NF; f++) acc += s_I[f] * (double)wrow[f];
            s_g[t] = (acc / stot + (double)bg[t]) * (1.0 / 0.07);
        }
        __syncthreads();
        if (t == 0) {
            double c0 = -1e300, c1 = -1e300; int j0 = 0, j1 = 0;
            for (int i = 0; i < 16; i++) {
                double v = s_g[i];
                if (v > c0) { c1 = c0; j1 = j0; c0 = v; j0 = i; }
                else if (v > c1) { c1 = v; j1 = i; }
            }
            double e1 = exp(c1 - c0);
            float w0f = (float)(1.0 / (1.0 + e1));
            int newpid = j0 * 16 + j1;
            int old = rec[b];
            if (newpid != old) {
                atomicSub(&pcnt[old << 4], 1);
                atomicAdd(&pcnt[newpid << 4], 1);
                rec[b] = newpid;
            }
            ((float*)(hdr + b))[3] = w0f;
        }
        __syncthreads();
    }
}

// Scan pair counts -> pbase/tickets AND flat chunk descriptors.
__global__ __launch_bounds__(256) void k_scan(
    const int* __restrict__ pcnt, int* __restrict__ pbase, int* __restrict__ ptk,
    int* __restrict__ desc, int* __restrict__ nchk)
{
    __shared__ int s[256], c[256];
    const int t = threadIdx.x;
    const int n = pcnt[t << 4];
    s[t] = n;
    c[t] = (n + 63) >> 6;
    __syncthreads();
    for (int off = 1; off < 256; off <<= 1) {
        int v1 = (t >= off) ? s[t - off] : 0;
        int v2 = (t >= off) ? c[t - off] : 0;
        __syncthreads();
        s[t] += v1; c[t] += v2;
        __syncthreads();
    }
    int excl = t ? s[t - 1] : 0;
    int cexcl = t ? c[t - 1] : 0;
    pbase[t] = excl;
    ptk[t << 4] = excl;
    int myc = (n + 63) >> 6;
    for (int j = 0; j < myc; j++) desc[cexcl + j] = (t << 16) | j;
    if (t == 255) *nchk = cexcl + myc;
}

// Scatter rows into compact pair-bucketed list.
__global__ __launch_bounds__(256) void k_scatter(
    const int* __restrict__ rec, int* __restrict__ ptk, int* __restrict__ ridx)
{
    __shared__ int h[256], base_[256];
    const int t = threadIdx.x;
    const int b = blockIdx.x * 256 + t;
    h[t] = 0;
    __syncthreads();
    int pid = rec[b];
    int lo = atomicAdd(&h[pid], 1);
    __syncthreads();
    if (h[t]) base_[t] = atomicAdd(&ptk[t << 4], h[t]);
    __syncthreads();
    ridx[base_[pid] + lo] = b;
}

// Pair-bucket MFMA GEMM with register prefetch (T14 async-stage split).
// XB=1: A read as bf16 from xb16 (K-permuted, matching Wrb). XB=0: f32 x +
// linear Wrb.
template<int XB>
__global__ __launch_bounds__(256) void k_gemm(
    const float* __restrict__ x, const unsigned short* __restrict__ xb16,
    const unsigned short* __restrict__ Wrb,
    const float* __restrict__ br, const float* __restrict__ Ssum,
    const float4* __restrict__ hdr, float* __restrict__ out,
    const int* __restrict__ pcnt, const int* __restrict__ pbase,
    const int* __restrict__ ridx,
    const int* __restrict__ desc, const int* __restrict__ nchk)
{
    __shared__ __align__(16) unsigned short sA[64 * 72];      // [r][k]
    __shared__ __align__(16) unsigned short sB[2][96 * 72];   // [ex][p][k]
    __shared__ int    s_idx[64];
    __shared__ float4 s_hdr[64];
    __shared__ float  s_br[2][96], s_S[2][96];
    if ((int)blockIdx.x >= *nchk) return;
    const int d = desc[blockIdx.x];
    const int pid = d >> 16, cc = d & 0xffff;
    const int n = pcnt[pid << 4];
    const int base = pbase[pid];
    const int i0 = pid >> 4, i1 = pid & 15;
    const int t = threadIdx.x;
    const int lane = t & 63, wv = t >> 6;
    const int quad = lane >> 4, l16 = lane & 15;
    const int ar = t >> 2, asub = t & 3;
    if (t < 96) {
        s_br[0][t] = (i0 < NEL) ? br[i0 * NP + t] : 0.f;
        s_S [0][t] = (i0 < NEL) ? Ssum[i0 * NP + t] : 0.f;
        s_br[1][t] = (i1 < NEL) ? br[i1 * NP + t] : 0.f;
        s_S [1][t] = (i1 < NEL) ? Ssum[i1 * NP + t] : 0.f;
    }
    if (t < 64) {
        int g = cc * 64 + t;
        bool vld = g < n;
        int row = vld ? ridx[base + g] : -1;
        s_idx[t] = row;
        s_hdr[t] = vld ? hdr[row] : make_float4(0.f, 0.f, 0.f, 0.f);
    }
    __syncthreads();

    f32x4 acc[2][6];
#pragma unroll
    for (int ex = 0; ex < 2; ex++)
#pragma unroll
        for (int j = 0; j < 6; j++) acc[ex][j] = (f32x4){0.f, 0.f, 0.f, 0.f};

    int rr = s_idx[ar]; if (rr < 0) rr = s_idx[0];

    unsigned boff[6];
    unsigned short* bdst[6];
    const unsigned short* wb[2];
    wb[0] = Wrb + (size_t)i0 * NP * NL;
    wb[1] = Wrb + (size_t)i1 * NP * NL;
    int bex[6];
#pragma unroll
    for (int it = 0; it < 6; it++) {
        int ex = (it >= 3);
        int fl = t + (it - 3 * ex) * 256;
        int p = fl >> 3, kg = fl & 7;
        bex[it] = ex;
        boff[it] = (unsigned)(p * NL + kg * 8);
        bdst[it] = &sB[ex][p * 72 + kg * 8];
    }
    unsigned short* adst = sA + ar * 72 + asub * 16;

    const unsigned short* xrow16 = xb16 + (size_t)rr * NL + asub * 16;
    const float* xrowf = x + (size_t)rr * NL + asub * 16;

    bf16x8 aR[2]; float4 fA[4]; bf16x8 bR[6];

    if constexpr (XB) {
        aR[0] = *(const bf16x8*)(xrow16);
        aR[1] = *(const bf16x8*)(xrow16 + 8);
    } else {
#pragma unroll
        for (int i = 0; i < 4; i++) fA[i] = ((const float4*)xrowf)[i];
    }
#pragma unroll
    for (int it = 0; it < 6; it++) bR[it] = *(const bf16x8*)(wb[bex[it]] + boff[it]);

    for (int kb = 0; kb < NL; kb += 64) {
        if constexpr (XB) {
            *(bf16x8*)adst       = aR[0];
            *(bf16x8*)(adst + 8) = aR[1];
        } else {
            unsigned short tmp[16];
#pragma unroll
            for (int i = 0; i < 4; i++) {
                float4 v = fA[i];
                tmp[i * 4 + 0] = f2bf(v.x); tmp[i * 4 + 1] = f2bf(v.y);
                tmp[i * 4 + 2] = f2bf(v.z); tmp[i * 4 + 3] = f2bf(v.w);
            }
            *(bf16x8*)adst       = *(bf16x8*)tmp;
            *(bf16x8*)(adst + 8) = *(bf16x8*)(tmp + 8);
        }
#pragma unroll
        for (int it = 0; it < 6; it++) *(bf16x8*)bdst[it] = bR[it];
        __syncthreads();

        const int kn = kb + 64;
        if (kn < NL) {
            if constexpr (XB) {
                aR[0] = *(const bf16x8*)(xrow16 + kn);
                aR[1] = *(const bf16x8*)(xrow16 + kn + 8);
            } else {
#pragma unroll
                for (int i = 0; i < 4; i++) fA[i] = ((const float4*)(xrowf + kn))[i];
            }
#pragma unroll
            for (int it = 0; it < 6; it++)
                bR[it] = *(const bf16x8*)(wb[bex[it]] + boff[it] + kn);
        }

#pragma unroll
        for (int ks = 0; ks < 2; ks++) {
            bf16x8 af = *(const bf16x8*)(sA + (wv * 16 + l16) * 72 + ks * 32 + quad * 8);
#pragma unroll
            for (int ex = 0; ex < 2; ex++)
#pragma unroll
                for (int nt = 0; nt < 6; nt++) {
                    bf16x8 bf = *(const bf16x8*)(&sB[ex][(nt * 16 + l16) * 72 + ks * 32 + quad * 8]);
                    acc[ex][nt] = __builtin_amdgcn_mfma_f32_16x16x32_bf16(af, bf, acc[ex][nt], 0, 0, 0);
                }
        }
        __syncthreads();
    }
#pragma unroll
    for (int i = 0; i < 4; i++) {
        int rloc = wv * 16 + quad * 4 + i;
        int row = s_idx[rloc];
        if (row >= 0) {
            float4 h = s_hdr[rloc];
            float mu = h.x, sd = h.y, last = h.z, w0 = h.w, w1 = 1.f - w0;
            float* orow = out + (size_t)row * NP;
#pragma unroll
            for (int nt = 0; nt < 6; nt++) {
                int p = nt * 16 + l16;
                float v0 = (i0 < NEL) ? (mu + s_br[0][p] * sd - mu * s_S[0][p] + acc[0][nt][i])
                                      : (i0 == NEL ? mu : last);
                float v1 = (i1 < NEL) ? (mu + s_br[1][p] * sd - mu * s_S[1][p] + acc[1][nt][i])
                                      : (i1 == NEL ? mu : last);
                orow[p] = w0 * v0 + w1 * v1;
            }
        }
    }
}

extern "C" void kernel_launch(void* const* d_in, const int* in_sizes, int n_in,
                              void* d_out, int out_size, void* d_ws, size_t ws_size,
                              hipStream_t stream)
{
    const float* x  = (const float*)d_in[0];
    const float* Wg = (const float*)d_in[1];
    const float* bg = (const float*)d_in[2];
    const float* Wr = (const float*)d_in[3];
    const float* br = (const float*)d_in[4];
    float* out = (float*)d_out;
    char* ws = (char*)d_ws;

    int*     pcnt     = (int*)(ws + WS_PCNT);
    int*     ptk      = (int*)(ws + WS_PTK);
    int*     pbase    = (int*)(ws + WS_PBASE);
    int*     flagcnt  = (int*)(ws + WS_FLAGCNT);
    int*     nchk     = (int*)(ws + WS_NCHK);
    int*     flaglist = (int*)(ws + WS_FLAG);
    float*   Ssum     = (float*)(ws + WS_SSUM);
    float*   WgE      = (float*)(ws + WS_WGT);
    float*   bgT      = (float*)(ws + WS_BGT);
    float2*  twf      = (float2*)(ws + WS_TWF);
    double2* twd      = (double2*)(ws + WS_TWD);
    int*     rec      = (int*)(ws + WS_REC);
    float4*  hdr      = (float4*)(ws + WS_HDR);
    int*     ridx     = (int*)(ws + WS_RIDX);
    unsigned short* Wrb = (unsigned short*)(ws + WS_WRB);
    int*     desc     = (int*)(ws + WS_DESC);

    const size_t xb_bytes = (size_t)NB_B * NL * 2;
    const int use_xb = (ws_size >= (size_t)WS_XB16 + xb_bytes);
    unsigned short* xb16 = use_xb ? (unsigned short*)(ws + WS_XB16) : (unsigned short*)0;

    k_prep<<<dim3(768), dim3(256), 0, stream>>>(Wg, bg, Wr, Ssum, WgE, bgT, twf, twd,
                                                pcnt, flagcnt, (ushort4*)Wrb, use_xb);
    k_gate<<<dim3(NB_B / 8), dim3(256), 0, stream>>>(x, (const float4*)WgE, bgT, twf,
                                                     rec, hdr, flaglist, flagcnt, pcnt, xb16);
    k_refine<<<dim3(512), dim3(256), 0, stream>>>(x, twd, Wg, bg, rec, hdr,
                                                  flaglist, flagcnt, pcnt);
    k_scan<<<dim3(1), dim3(256), 0, stream>>>(pcnt, pbase, ptk, desc, nchk);
    k_scatter<<<dim3(NB_B / 256), dim3(256), 0, stream>>>(rec, ptk, ridx);
    if (use_xb)
        k_gemm<1><<<dim3(MAXCHK), dim3(256), 0, stream>>>(x, xb16, Wrb, br, Ssum, hdr, out,
                                                          pcnt, pbase, ridx, desc, nchk);
    else
        k_gemm<0><<<dim3(MAXCHK), dim3(256), 0, stream>>>(x, xb16, Wrb, br, Ssum, hdr, out,
                                                          pcnt, pbase, ridx, desc, nchk);
}

// Round 4
// 310.793 us; speedup vs baseline: 1.0326x; 1.0326x over previous
//
#include <hip/hip_runtime.h>
#include <math.h>

#define NB_B 65536
#define NL   512
#define NP   96
#define NE   16
#define NEL  14
#define NF   256
#define TEMP_INV (1.0f/0.07f)
#define TAU  1e-5f
#define PI_D 3.14159265358979323846
#define MAXCHK 1280

typedef __attribute__((ext_vector_type(8))) short bf16x8;
typedef __attribute__((ext_vector_type(4))) float f32x4;

// ---------------- workspace layout (bytes) ----------------
// K-PERMUTATION: when xb16 is active, both xb16 rows and Wrb rows store the
// 512 K-elements in permuted order slot s = l*8+k  <->  orig = (s&7)*64+(s>>3).
// Dot products over K are permutation-invariant, so k_gemm is unchanged.

#define WS_PCNT     0
#define WS_PTK      16384
#define WS_PBASE    32768
#define WS_FLAGCNT  33792
#define WS_NCHK     33824
#define WS_FLAG     33856
#define WS_SSUM     296000
#define WS_WGT      301376
#define WS_BGT      317760
#define WS_TWF      317824
#define WS_TWD      319872
#define WS_REC      328064
#define WS_HDR      590208
#define WS_RIDX     1638784
#define WS_WRB      1900928
#define WS_DESC     3473792
#define WS_XB16     3480064

__device__ __forceinline__ unsigned short f2bf(float f) {
    unsigned u = __float_as_uint(f);
    unsigned r = (u + 0x7fffu + ((u >> 16) & 1u)) >> 16;
    return (unsigned short)r;
}

// prep + Wr f32->bf16 cvt merged. 768 blocks. perm=1: K-permuted Wrb layout.
__global__ __launch_bounds__(256) void k_prep(
    const float* __restrict__ Wg, const float* __restrict__ bg,
    const float* __restrict__ Wr,
    float* __restrict__ Ssum, float* __restrict__ WgE, float* __restrict__ bgT,
    double2* __restrict__ twd,
    int* __restrict__ pcnt, int* __restrict__ flagcnt,
    ushort4* __restrict__ Wrb, int perm)
{
    int g = blockIdx.x * 256 + threadIdx.x;
    {
        ushort4 o = make_ushort4(0, 0, 0, 0);
        if (g < NEL * NP * NL / 4) {
            float4 v;
            if (perm) {
                // output slots 4sq..4sq+3 of row; slot s -> orig (s&7)*64+(s>>3)
                int row = g >> 7, sq = g & 127;
                int ll = sq >> 1, kb = (sq & 1) * 4;
                const float* wr = Wr + (size_t)row * NL + ll;
                v.x = wr[(kb + 0) * 64]; v.y = wr[(kb + 1) * 64];
                v.z = wr[(kb + 2) * 64]; v.w = wr[(kb + 3) * 64];
            } else {
                v = ((const float4*)Wr)[g];
            }
            o.x = f2bf(v.x); o.y = f2bf(v.y); o.z = f2bf(v.z); o.w = f2bf(v.w);
        }
        Wrb[g] = o;
    }
    if (g < NEL * NP) {
        const float4* w = (const float4*)(Wr + (size_t)g * NL);
        float s = 0.f;
        for (int i = 0; i < NL / 4; i++) { float4 v = w[i]; s += v.x + v.y + v.z + v.w; }
        Ssum[g] = s;
    }
    if (g < 4096) {
        int c = g & 3, e = (g >> 2) & 15, f4 = g >> 6;
        WgE[g] = Wg[e * NF + f4 * 4 + c] * TEMP_INV;
    }
    if (g < 512) {
        double a = -2.0 * PI_D * (double)g / 512.0;
        twd[g] = make_double2(cos(a), sin(a));
    }
    if (g < 256) pcnt[g << 4] = 0;
    if (g < NE) bgT[g] = bg[g] * TEMP_INV;
    if (g == 300) *flagcnt = 0;
}

// Pack-2 real FFT per wave. Twiddles COMPUTED per-lane via v_sin/v_cos
// (no table, no LDS staging, no __syncthreads; removes the 160-cache-line
// twiddle gather burst per wave that R3's counters exposed).
// xb16 emitted as 2 coalesced b128 stores per lane (K-permuted layout),
// packed with v_cvt_pk_bf16_f32.
__global__ __launch_bounds__(256) void k_gate(
    const float* __restrict__ x,
    const float4* __restrict__ WgE4, const float* __restrict__ bgT,
    int* __restrict__ rec, float4* __restrict__ hdr,
    int* __restrict__ flaglist, int* __restrict__ flagcnt,
    int* __restrict__ pcnt, unsigned short* __restrict__ xb16)
{
    __shared__ __align__(16) float2 s_z[4][576];
    float* s_Iv = (float*)&s_z[0][0];

    const int t = threadIdx.x;
    const int wv = t >> 6, l = t & 63;
    const int b0 = blockIdx.x * 8 + wv * 2;

    // twiddles computed in registers: tw(g) = (cos, sin)(-2*pi*g/512)
    const float kAng = -6.283185307179586f / 512.0f;
    auto mktw = [&](int g) {
        float s_, c_;
        __sincosf((float)g * kAng, &s_, &c_);
        return make_float2(c_, s_);
    };
    float2 tw0[4], tw1[2];
#pragma unroll
    for (int k = 0; k < 4; k++) tw0[k] = mktw(k * 64 + l);
    tw1[0] = mktw(2 * l);
    tw1[1] = mktw(128 + 2 * l);
    const float2 w2 = mktw(l << 2);
    float2 wst[5];
    wst[0] = mktw((l & 31) << 3);
    wst[1] = mktw((l & 15) << 4);
    wst[2] = mktw((l & 7) << 5);
    wst[3] = mktw((l & 3) << 6);
    wst[4] = mktw((l & 1) << 7);

    const float* xa = x + (size_t)b0 * NL;
    const float* xb = xa + NL;
    float xr[8], xi[8];
#pragma unroll
    for (int k = 0; k < 8; k++) { xr[k] = xa[k * 64 + l]; xi[k] = xb[k * 64 + l]; }
    const float last_a = __shfl(xr[7], 63);
    const float last_b = __shfl(xi[7], 63);

    if (xb16) {   // K-permuted bf16 copy: lane stores its 8 values contiguously
        unsigned pa_[4], pb_[4];
#pragma unroll
        for (int j = 0; j < 4; j++) {
            asm("v_cvt_pk_bf16_f32 %0, %1, %2" : "=v"(pa_[j]) : "v"(xr[2 * j]), "v"(xr[2 * j + 1]));
            asm("v_cvt_pk_bf16_f32 %0, %1, %2" : "=v"(pb_[j]) : "v"(xi[2 * j]), "v"(xi[2 * j + 1]));
        }
        *(uint4*)(xb16 + (size_t)b0 * NL + l * 8)       = *(uint4*)pa_;
        *(uint4*)(xb16 + (size_t)(b0 + 1) * NL + l * 8) = *(uint4*)pb_;
    }

    // ---- DIF FFT (complex), natural in, bit-reversed out ----
#pragma unroll
    for (int k = 0; k < 4; k++) {                       // stage 0: half=256
        float2 w = tw0[k];
        float ur = xr[k], ui = xi[k], vr = xr[k + 4], vi = xi[k + 4];
        xr[k] = ur + vr; xi[k] = ui + vi;
        float dr = ur - vr, di = ui - vi;
        xr[k + 4] = dr * w.x - di * w.y; xi[k + 4] = dr * w.y + di * w.x;
    }
    {                                                   // stage 1: half=128
        const int kk[4] = {0, 1, 4, 5};
#pragma unroll
        for (int g2 = 0; g2 < 4; g2++) {
            int k = kk[g2];
            float2 w = tw1[k & 1];
            float ur = xr[k], ui = xi[k], vr = xr[k + 2], vi = xi[k + 2];
            xr[k] = ur + vr; xi[k] = ui + vi;
            float dr = ur - vr, di = ui - vi;
            xr[k + 2] = dr * w.x - di * w.y; xi[k + 2] = dr * w.y + di * w.x;
        }
    }
    {                                                   // stage 2: half=64
#pragma unroll
        for (int k = 0; k < 8; k += 2) {
            float ur = xr[k], ui = xi[k], vr = xr[k + 1], vi = xi[k + 1];
            xr[k] = ur + vr; xi[k] = ui + vi;
            float dr = ur - vr, di = ui - vi;
            xr[k + 1] = dr * w2.x - di * w2.y; xi[k + 1] = dr * w2.y + di * w2.x;
        }
    }
#pragma unroll
    for (int st = 3; st < 8; st++) {                    // stages 3..7 cross-lane
        const int half = 256 >> st;
        const float2 w = wst[st - 3];
        const bool up = (l & half) != 0;
        const float sg = up ? -1.f : 1.f;
        const float cc = up ? w.x : 1.f;
        const float ss = up ? w.y : 0.f;
#pragma unroll
        for (int k = 0; k < 8; k++) {
            float pr = __shfl_xor(xr[k], half);
            float pi = __shfl_xor(xi[k], half);
            float tr = fmaf(sg, xr[k], pr);
            float ti = fmaf(sg, xi[k], pi);
            xr[k] = tr * cc - ti * ss;
            xi[k] = tr * ss + ti * cc;
        }
    }
    {                                                   // stage 8: half=1, w=(1,0)
        const float sg = (l & 1) ? -1.f : 1.f;
#pragma unroll
        for (int k = 0; k < 8; k++) {
            float pr = __shfl_xor(xr[k], 1);
            float pi = __shfl_xor(xi[k], 1);
            xr[k] = fmaf(sg, xr[k], pr);
            xi[k] = fmaf(sg, xi[k], pi);
        }
    }

#pragma unroll
    for (int k = 0; k < 8; k++) {
        int i = k * 64 + l;
        s_z[wv][i + (i >> 3)] = make_float2(xr[k], xi[k]);
    }
    // s_z[wv] is wave-private: no barrier needed.

    // conjugate-symmetry split: lane l owns bins f = 4l..4l+3
    float Ia[4], Ib[4];
    float psa = 0.f, psb = 0.f;
#pragma unroll
    for (int j = 0; j < 4; j++) {
        int f = (l << 2) | j;
        int i1_ = (int)(__brev((unsigned)f) >> 23);
        int i2_ = (int)(__brev((unsigned)((512 - f) & 511)) >> 23);
        float2 z1 = s_z[wv][i1_ + (i1_ >> 3)];
        float2 z2 = s_z[wv][i2_ + (i2_ >> 3)];
        float pr_ = z1.x + z2.x, qm = z1.y - z2.y;
        float qp = z1.y + z2.y, pm = z1.x - z2.x;
        float va = pr_ * pr_ + qm * qm;
        float vb = qp * qp + pm * pm;
        if (f == 0) { va = 0.f; vb = 0.f; }   // centering only affects bin 0
        Ia[j] = va; Ib[j] = vb;
        psa += va; psb += vb;
    }
#pragma unroll
    for (int m = 1; m < 64; m <<= 1) {
        psa += __shfl_xor(psa, m); psb += __shfl_xor(psb, m);
    }
    const float psa_raw = psa, psb_raw = psb;
    if (psa == 0.f) psa = 1.f;
    if (psb == 0.f) psb = 1.f;
    const float inv_a = 1.f / psa, inv_b = 1.f / psb;

    const float2 Z0   = s_z[wv][0];
    const float2 Z256 = s_z[wv][1];

    float* wI = s_Iv + wv * 1152;
    const int io = (l << 2) + ((l >> 4) << 2);
    *(float4*)(wI + io)       = make_float4(Ia[0], Ia[1], Ia[2], Ia[3]);
    *(float4*)(wI + 272 + io) = make_float4(Ib[0], Ib[1], Ib[2], Ib[3]);

    // gate matmul: lane (e = l&15, cq = l>>4) sums quarter cq for expert e
    const int e16 = l & 15, cq = l >> 4;
    const float bgv = bgT[e16];
    float accA = 0.f, accB = 0.f;
    const float* rA = wI + cq * 68;
    const float* rB = rA + 272;
#pragma unroll 4
    for (int jj = 0; jj < 16; jj++) {
        float4 ia = *(const float4*)(rA + 4 * jj);
        float4 ib = *(const float4*)(rB + 4 * jj);
        float4 w = WgE4[(cq * 16 + jj) * 16 + e16];
        accA += ia.x * w.x + ia.y * w.y + ia.z * w.z + ia.w * w.w;
        accB += ib.x * w.x + ib.y * w.y + ib.z * w.z + ib.w * w.w;
    }
    accA += __shfl_xor(accA, 16); accA += __shfl_xor(accA, 32);
    accB += __shfl_xor(accB, 16); accB += __shfl_xor(accB, 32);

    float v = ((l & 16) ? accB * inv_b : accA * inv_a) + bgv;

    // parallel top-3 within 16-lane group, first-index tie-break
    float b0v = v; int b0i = e16;
#pragma unroll
    for (int m = 1; m < 16; m <<= 1) {
        float ov = __shfl_xor(b0v, m); int oi = __shfl_xor(b0i, m);
        if (ov > b0v || (ov == b0v && oi < b0i)) { b0v = ov; b0i = oi; }
    }
    float v1 = (e16 == b0i) ? -1e30f : v;
    float b1v = v1; int b1i = e16;
#pragma unroll
    for (int m = 1; m < 16; m <<= 1) {
        float ov = __shfl_xor(b1v, m); int oi = __shfl_xor(b1i, m);
        if (ov > b1v || (ov == b1v && oi < b1i)) { b1v = ov; b1i = oi; }
    }
    float v2 = (e16 == b1i) ? -1e30f : v1;
    float b2v = v2;
#pragma unroll
    for (int m = 1; m < 16; m <<= 1) {
        float ov = __shfl_xor(b2v, m);
        b2v = fmaxf(b2v, ov);
    }

    if (l == 0 || l == 16) {
        const int r = l >> 4;
        const int b = b0 + r;
        const float mu = (r ? Z0.y : Z0.x) * (1.f / 512.f);
        const float Jv = r ? Z256.y : Z256.x;
        const float ps = r ? psb_raw : psa_raw;
        const float sd = sqrtf((0.5f * ps + Jv * Jv) * (1.f / 262144.f) + 1e-5f);
        const float last = r ? last_b : last_a;
        const float w0 = 1.f / (1.f + expf(b1v - b0v));
        const int pid = b0i * 16 + b1i;
        rec[b] = pid;
        hdr[b] = make_float4(mu, sd, last, w0);
        atomicAdd(&pcnt[pid << 4], 1);
        if (b1v - b2v < TAU) {
            int pos = atomicAdd(flagcnt, 1);
            flaglist[pos] = b;
        }
    }
}

// f64 phasor-DFT refinement for flagged rows; fixes pair counts on reclass.
__global__ __launch_bounds__(256) void k_refine(
    const float* __restrict__ x, const double2* __restrict__ twd,
    const float* __restrict__ Wg, const float* __restrict__ bg,
    int* __restrict__ rec, float4* __restrict__ hdr,
    const int* __restrict__ flaglist, const int* __restrict__ flagcnt,
    int* __restrict__ pcnt)
{
    __shared__ double s_x[512];
    __shared__ double s_I[256];
    __shared__ double s_red[16];
    __shared__ double s_g[16];
    const int nf = *flagcnt;
    const int t = threadIdx.x;
    const int wid = t >> 6, lane = t & 63;
    for (int fi = blockIdx.x; fi < nf; fi += gridDim.x) {
        const int b = flaglist[fi];
        const float* xp = x + (size_t)b * NL;
        double v0 = (double)xp[t], v1 = (double)xp[t + 256];
        double lsum = v0 + v1;
        for (int m = 1; m < 64; m <<= 1) lsum += __shfl_xor(lsum, m);
        if (lane == 0) s_red[wid] = lsum;
        __syncthreads();
        double mu = (s_red[0] + s_red[1] + s_red[2] + s_red[3]) * (1.0 / 512.0);
        s_x[t] = v0 - mu; s_x[t + 256] = v1 - mu;
        __syncthreads();
        double2 w = twd[t];
        double pr = 1.0, pi = 0.0, cr = 0.0, ci = 0.0;
        for (int n = 0; n < 512; n++) {
            double xv = s_x[n];
            cr += xv * pr; ci += xv * pi;
            double t2 = pr * w.x - pi * w.y;
            pi = pr * w.y + pi * w.x;
            pr = t2;
        }
        double I = cr * cr + ci * ci;
        s_I[t] = I;
        double ls = I;
        for (int m = 1; m < 64; m <<= 1) ls += __shfl_xor(ls, m);
        if (lane == 0) s_red[8 + wid] = ls;
        __syncthreads();
        double stot = s_red[8] + s_red[9] + s_red[10] + s_red[11];
        if (stot == 0.0) stot = 1.0;
        if (t < 16) {
            double acc = 0.0;
            const float* wrow = Wg + t * NF;
            for (int f = 0; f < NF; f++) acc += s_I[f] * (double)wrow[f];
            s_g[t] = (acc / stot + (double)bg[t]) * (1.0 / 0.07);
        }
        __syncthreads();
        if (t == 0) {
            double c0 = -1e300, c1 = -1e300; int j0 = 0, j1 = 0;
            for (int i = 0; i < 16; i++) {
                double v = s_g[i];
                if (v > c0) { c1 = c0; j1 = j0; c0 = v; j0 = i; }
                else if (v > c1) { c1 = v; j1 = i; }
            }
            double e1 = exp(c1 - c0);
            float w0f = (float)(1.0 / (1.0 + e1));
            int newpid = j0 * 16 + j1;
            int old = rec[b];
            if (newpid != old) {
                atomicSub(&pcnt[old << 4], 1);
                atomicAdd(&pcnt[newpid << 4], 1);
                rec[b] = newpid;
            }
            ((float*)(hdr + b))[3] = w0f;
        }
        __syncthreads();
    }
}

// Scan pair counts -> pbase/tickets AND flat chunk descriptors.
__global__ __launch_bounds__(256) void k_scan(
    const int* __restrict__ pcnt, int* __restrict__ pbase, int* __restrict__ ptk,
    int* __restrict__ desc, int* __restrict__ nchk)
{
    __shared__ int s[256], c[256];
    const int t = threadIdx.x;
    const int n = pcnt[t << 4];
    s[t] = n;
    c[t] = (n + 63) >> 6;
    __syncthreads();
    for (int off = 1; off < 256; off <<= 1) {
        int v1 = (t >= off) ? s[t - off] : 0;
        int v2 = (t >= off) ? c[t - off] : 0;
        __syncthreads();
        s[t] += v1; c[t] += v2;
        __syncthreads();
    }
    int excl = t ? s[t - 1] : 0;
    int cexcl = t ? c[t - 1] : 0;
    pbase[t] = excl;
    ptk[t << 4] = excl;
    int myc = (n + 63) >> 6;
    for (int j = 0; j < myc; j++) desc[cexcl + j] = (t << 16) | j;
    if (t == 255) *nchk = cexcl + myc;
}

// Scatter rows into compact pair-bucketed list.
__global__ __launch_bounds__(256) void k_scatter(
    const int* __restrict__ rec, int* __restrict__ ptk, int* __restrict__ ridx)
{
    __shared__ int h[256], base_[256];
    const int t = threadIdx.x;
    const int b = blockIdx.x * 256 + t;
    h[t] = 0;
    __syncthreads();
    int pid = rec[b];
    int lo = atomicAdd(&h[pid], 1);
    __syncthreads();
    if (h[t]) base_[t] = atomicAdd(&ptk[t << 4], h[t]);
    __syncthreads();
    ridx[base_[pid] + lo] = b;
}

// Pair-bucket MFMA GEMM with register prefetch (T14 async-stage split).
// XB=1: A read as bf16 from xb16 (K-permuted, matching Wrb). XB=0: f32 x +
// linear Wrb.
template<int XB>
__global__ __launch_bounds__(256) void k_gemm(
    const float* __restrict__ x, const unsigned short* __restrict__ xb16,
    const unsigned short* __restrict__ Wrb,
    const float* __restrict__ br, const float* __restrict__ Ssum,
    const float4* __restrict__ hdr, float* __restrict__ out,
    const int* __restrict__ pcnt, const int* __restrict__ pbase,
    const int* __restrict__ ridx,
    const int* __restrict__ desc, const int* __restrict__ nchk)
{
    __shared__ __align__(16) unsigned short sA[64 * 72];      // [r][k]
    __shared__ __align__(16) unsigned short sB[2][96 * 72];   // [ex][p][k]
    __shared__ int    s_idx[64];
    __shared__ float4 s_hdr[64];
    __shared__ float  s_br[2][96], s_S[2][96];
    if ((int)blockIdx.x >= *nchk) return;
    const int d = desc[blockIdx.x];
    const int pid = d >> 16, cc = d & 0xffff;
    const int n = pcnt[pid << 4];
    const int base = pbase[pid];
    const int i0 = pid >> 4, i1 = pid & 15;
    const int t = threadIdx.x;
    const int lane = t & 63, wv = t >> 6;
    const int quad = lane >> 4, l16 = lane & 15;
    const int ar = t >> 2, asub = t & 3;
    if (t < 96) {
        s_br[0][t] = (i0 < NEL) ? br[i0 * NP + t] : 0.f;
        s_S [0][t] = (i0 < NEL) ? Ssum[i0 * NP + t] : 0.f;
        s_br[1][t] = (i1 < NEL) ? br[i1 * NP + t] : 0.f;
        s_S [1][t] = (i1 < NEL) ? Ssum[i1 * NP + t] : 0.f;
    }
    if (t < 64) {
        int g = cc * 64 + t;
        bool vld = g < n;
        int row = vld ? ridx[base + g] : -1;
        s_idx[t] = row;
        s_hdr[t] = vld ? hdr[row] : make_float4(0.f, 0.f, 0.f, 0.f);
    }
    __syncthreads();

    f32x4 acc[2][6];
#pragma unroll
    for (int ex = 0; ex < 2; ex++)
#pragma unroll
        for (int j = 0; j < 6; j++) acc[ex][j] = (f32x4){0.f, 0.f, 0.f, 0.f};

    int rr = s_idx[ar]; if (rr < 0) rr = s_idx[0];

    unsigned boff[6];
    unsigned short* bdst[6];
    const unsigned short* wb[2];
    wb[0] = Wrb + (size_t)i0 * NP * NL;
    wb[1] = Wrb + (size_t)i1 * NP * NL;
    int bex[6];
#pragma unroll
    for (int it = 0; it < 6; it++) {
        int ex = (it >= 3);
        int fl = t + (it - 3 * ex) * 256;
        int p = fl >> 3, kg = fl & 7;
        bex[it] = ex;
        boff[it] = (unsigned)(p * NL + kg * 8);
        bdst[it] = &sB[ex][p * 72 + kg * 8];
    }
    unsigned short* adst = sA + ar * 72 + asub * 16;

    const unsigned short* xrow16 = xb16 + (size_t)rr * NL + asub * 16;
    const float* xrowf = x + (size_t)rr * NL + asub * 16;

    bf16x8 aR[2]; float4 fA[4]; bf16x8 bR[6];

    if constexpr (XB) {
        aR[0] = *(const bf16x8*)(xrow16);
        aR[1] = *(const bf16x8*)(xrow16 + 8);
    } else {
#pragma unroll
        for (int i = 0; i < 4; i++) fA[i] = ((const float4*)xrowf)[i];
    }
#pragma unroll
    for (int it = 0; it < 6; it++) bR[it] = *(const bf16x8*)(wb[bex[it]] + boff[it]);

    for (int kb = 0; kb < NL; kb += 64) {
        if constexpr (XB) {
            *(bf16x8*)adst       = aR[0];
            *(bf16x8*)(adst + 8) = aR[1];
        } else {
            unsigned short tmp[16];
#pragma unroll
            for (int i = 0; i < 4; i++) {
                float4 v = fA[i];
                tmp[i * 4 + 0] = f2bf(v.x); tmp[i * 4 + 1] = f2bf(v.y);
                tmp[i * 4 + 2] = f2bf(v.z); tmp[i * 4 + 3] = f2bf(v.w);
            }
            *(bf16x8*)adst       = *(bf16x8*)tmp;
            *(bf16x8*)(adst + 8) = *(bf16x8*)(tmp + 8);
        }
#pragma unroll
        for (int it = 0; it < 6; it++) *(bf16x8*)bdst[it] = bR[it];
        __syncthreads();

        const int kn = kb + 64;
        if (kn < NL) {
            if constexpr (XB) {
                aR[0] = *(const bf16x8*)(xrow16 + kn);
                aR[1] = *(const bf16x8*)(xrow16 + kn + 8);
            } else {
#pragma unroll
                for (int i = 0; i < 4; i++) fA[i] = ((const float4*)(xrowf + kn))[i];
            }
#pragma unroll
            for (int it = 0; it < 6; it++)
                bR[it] = *(const bf16x8*)(wb[bex[it]] + boff[it] + kn);
        }

#pragma unroll
        for (int ks = 0; ks < 2; ks++) {
            bf16x8 af = *(const bf16x8*)(sA + (wv * 16 + l16) * 72 + ks * 32 + quad * 8);
#pragma unroll
            for (int ex = 0; ex < 2; ex++)
#pragma unroll
                for (int nt = 0; nt < 6; nt++) {
                    bf16x8 bf = *(const bf16x8*)(&sB[ex][(nt * 16 + l16) * 72 + ks * 32 + quad * 8]);
                    acc[ex][nt] = __builtin_amdgcn_mfma_f32_16x16x32_bf16(af, bf, acc[ex][nt], 0, 0, 0);
                }
        }
        __syncthreads();
    }
#pragma unroll
    for (int i = 0; i < 4; i++) {
        int rloc = wv * 16 + quad * 4 + i;
        int row = s_idx[rloc];
        if (row >= 0) {
            float4 h = s_hdr[rloc];
            float mu = h.x, sd = h.y, last = h.z, w0 = h.w, w1 = 1.f - w0;
            float* orow = out + (size_t)row * NP;
#pragma unroll
            for (int nt = 0; nt < 6; nt++) {
                int p = nt * 16 + l16;
                float v0 = (i0 < NEL) ? (mu + s_br[0][p] * sd - mu * s_S[0][p] + acc[0][nt][i])
                                      : (i0 == NEL ? mu : last);
                float v1 = (i1 < NEL) ? (mu + s_br[1][p] * sd - mu * s_S[1][p] + acc[1][nt][i])
                                      : (i1 == NEL ? mu : last);
                orow[p] = w0 * v0 + w1 * v1;
            }
        }
    }
}

extern "C" void kernel_launch(void* const* d_in, const int* in_sizes, int n_in,
                              void* d_out, int out_size, void* d_ws, size_t ws_size,
                              hipStream_t stream)
{
    const float* x  = (const float*)d_in[0];
    const float* Wg = (const float*)d_in[1];
    const float* bg = (const float*)d_in[2];
    const float* Wr = (const float*)d_in[3];
    const float* br = (const float*)d_in[4];
    float* out = (float*)d_out;
    char* ws = (char*)d_ws;

    int*     pcnt     = (int*)(ws + WS_PCNT);
    int*     ptk      = (int*)(ws + WS_PTK);
    int*     pbase    = (int*)(ws + WS_PBASE);
    int*     flagcnt  = (int*)(ws + WS_FLAGCNT);
    int*     nchk     = (int*)(ws + WS_NCHK);
    int*     flaglist = (int*)(ws + WS_FLAG);
    float*   Ssum     = (float*)(ws + WS_SSUM);
    float*   WgE      = (float*)(ws + WS_WGT);
    float*   bgT      = (float*)(ws + WS_BGT);
    double2* twd      = (double2*)(ws + WS_TWD);
    int*     rec      = (int*)(ws + WS_REC);
    float4*  hdr      = (float4*)(ws + WS_HDR);
    int*     ridx     = (int*)(ws + WS_RIDX);
    unsigned short* Wrb = (unsigned short*)(ws + WS_WRB);
    int*     desc     = (int*)(ws + WS_DESC);

    const size_t xb_bytes = (size_t)NB_B * NL * 2;
    const int use_xb = (ws_size >= (size_t)WS_XB16 + xb_bytes);
    unsigned short* xb16 = use_xb ? (unsigned short*)(ws + WS_XB16) : (unsigned short*)0;

    k_prep<<<dim3(768), dim3(256), 0, stream>>>(Wg, bg, Wr, Ssum, WgE, bgT, twd,
                                                pcnt, flagcnt, (ushort4*)Wrb, use_xb);
    k_gate<<<dim3(NB_B / 8), dim3(256), 0, stream>>>(x, (const float4*)WgE, bgT,
                                                     rec, hdr, flaglist, flagcnt, pcnt, xb16);
    k_refine<<<dim3(512), dim3(256), 0, stream>>>(x, twd, Wg, bg, rec, hdr,
                                                  flaglist, flagcnt, pcnt);
    k_scan<<<dim3(1), dim3(256), 0, stream>>>(pcnt, pbase, ptk, desc, nchk);
    k_scatter<<<dim3(NB_B / 256), dim3(256), 0, stream>>>(rec, ptk, ridx);
    if (use_xb)
        k_gemm<1><<<dim3(MAXCHK), dim3(256), 0, stream>>>(x, xb16, Wrb, br, Ssum, hdr, out,
                                                          pcnt, pbase, ridx, desc, nchk);
    else
        k_gemm<0><<<dim3(MAXCHK), dim3(256), 0, stream>>>(x, xb16, Wrb, br, Ssum, hdr, out,
                                                          pcnt, pbase, ridx, desc, nchk);
}

// Round 5
// 296.667 us; speedup vs baseline: 1.0818x; 1.0476x over previous
//
#include <hip/hip_runtime.h>
#include <math.h>

#define NB_B 65536
#define NL   512
#define NP   96
#define NE   16
#define NEL  14
#define NF   256
#define TEMP_INV (1.0f/0.07f)
#define TAU  1e-5f
#define PI_D 3.14159265358979323846
#define MAXCHK 1536

typedef __attribute__((ext_vector_type(8))) short bf16x8;
typedef __attribute__((ext_vector_type(4))) float f32x4;

// ---------------- workspace layout (bytes) ----------------
// rec packing: rec[b] = (pid<<24) | lo, lo = per-pid arrival index from k_gate's
// atomicAdd. Scatter is then atomic-free: ridx[pbase[pid]+lo] = b.
// Refine reclass APPENDS (new lo on new pid) and records the old packed slot in
// holes[]; holes are patched to -1 (k_gemm skips row<0). Counts never shrink.
// K-PERMUTATION (xb16 active): xb16 and Wrb rows store K-elements in slot
// s = l*8+k <-> orig = (s&7)*64+(s>>3); dot products are permutation-invariant.

#define WS_PCNT     0
#define WS_HOLES    16384      // 4096 ints (reuses old ptk space)
#define WS_PBASE    32768
#define WS_FLAGCNT  33792
#define WS_NCHK     33824
#define WS_HOLECNT  33840
#define WS_FLAG     33856
#define WS_SSUM     296000
#define WS_WGT      301376
#define WS_BGT      317760
#define WS_TWD      319872
#define WS_REC      328064
#define WS_HDR      590208
#define WS_RIDX     1638784
#define WS_WRB      1900928
#define WS_DESC     3473792
#define WS_XB16     3480064

__device__ __forceinline__ unsigned short f2bf(float f) {
    unsigned u = __float_as_uint(f);
    unsigned r = (u + 0x7fffu + ((u >> 16) & 1u)) >> 16;
    return (unsigned short)r;
}

// prep + Wr f32->bf16 cvt merged. 768 blocks. perm=1: K-permuted Wrb layout.
// Ssum parallelized: 8 threads/row (16 float4 each + 3-level shuffle reduce).
__global__ __launch_bounds__(256) void k_prep(
    const float* __restrict__ Wg, const float* __restrict__ bg,
    const float* __restrict__ Wr,
    float* __restrict__ Ssum, float* __restrict__ WgE, float* __restrict__ bgT,
    double2* __restrict__ twd,
    int* __restrict__ pcnt, int* __restrict__ flagcnt, int* __restrict__ holecnt,
    ushort4* __restrict__ Wrb, int perm)
{
    int g = blockIdx.x * 256 + threadIdx.x;
    {
        ushort4 o = make_ushort4(0, 0, 0, 0);
        if (g < NEL * NP * NL / 4) {
            float4 v;
            if (perm) {
                int row = g >> 7, sq = g & 127;
                int ll = sq >> 1, kb = (sq & 1) * 4;
                const float* wr = Wr + (size_t)row * NL + ll;
                v.x = wr[(kb + 0) * 64]; v.y = wr[(kb + 1) * 64];
                v.z = wr[(kb + 2) * 64]; v.w = wr[(kb + 3) * 64];
            } else {
                v = ((const float4*)Wr)[g];
            }
            o.x = f2bf(v.x); o.y = f2bf(v.y); o.z = f2bf(v.z); o.w = f2bf(v.w);
        }
        Wrb[g] = o;
    }
    if (g < NEL * NP * 8) {
        int row = g >> 3, seg = g & 7;
        const float4* w = (const float4*)(Wr + (size_t)row * NL + seg * 64);
        float s = 0.f;
#pragma unroll
        for (int i = 0; i < 16; i++) { float4 v = w[i]; s += v.x + v.y + v.z + v.w; }
        s += __shfl_xor(s, 1); s += __shfl_xor(s, 2); s += __shfl_xor(s, 4);
        if (seg == 0) Ssum[row] = s;
    }
    if (g < 4096) {
        int c = g & 3, e = (g >> 2) & 15, f4 = g >> 6;
        WgE[g] = Wg[e * NF + f4 * 4 + c] * TEMP_INV;
    }
    if (g < 512) {
        double a = -2.0 * PI_D * (double)g / 512.0;
        twd[g] = make_double2(cos(a), sin(a));
    }
    if (g < 256) pcnt[g << 4] = 0;
    if (g < NE) bgT[g] = bg[g] * TEMP_INV;
    if (g == 300) *flagcnt = 0;
    if (g == 301) *holecnt = 0;
}

// Pack-2 real FFT per wave. 5 sincos + algebraically derived twiddles
// (tw0[2,3], tw1[1]: exact swizzles; w2: one squaring; wst[3,4]: constants).
// Emits packed rec (pid<<24|lo) with lo from the pcnt atomic.
__global__ __launch_bounds__(256) void k_gate(
    const float* __restrict__ x,
    const float4* __restrict__ WgE4, const float* __restrict__ bgT,
    int* __restrict__ rec, float4* __restrict__ hdr,
    int* __restrict__ flaglist, int* __restrict__ flagcnt,
    int* __restrict__ pcnt, unsigned short* __restrict__ xb16)
{
    __shared__ __align__(16) float2 s_z[4][576];
    float* s_Iv = (float*)&s_z[0][0];

    const int t = threadIdx.x;
    const int wv = t >> 6, l = t & 63;
    const int b0 = blockIdx.x * 8 + wv * 2;

    // twiddles: tw(g) = (cos, sin)(-2*pi*g/512)
    const float th = -6.283185307179586f / 512.0f;
    const float R2 = 0.70710678118654752f;
    float s1, c1; __sincosf((float)l * th, &s1, &c1);                    // tw(l)
    float s2, c2; __sincosf((float)(2 * l) * th, &s2, &c2);              // tw(2l)
    float sw0, cw0; __sincosf((float)((l & 31) << 3) * th, &sw0, &cw0);  // tw(8(l&31))
    float sw1, cw1; __sincosf((float)((l & 15) << 4) * th, &sw1, &cw1);  // tw(16(l&15))
    float sw2, cw2; __sincosf((float)((l & 7) << 5) * th, &sw2, &cw2);   // tw(32(l&7))
    float2 tw0[4];
    tw0[0] = make_float2(c1, s1);
    tw0[1] = make_float2(R2 * (c1 + s1), R2 * (s1 - c1));  // tw(l)*tw(64)
    tw0[2] = make_float2(s1, -c1);                          // tw(l)*tw(128)
    tw0[3] = make_float2(tw0[1].y, -tw0[1].x);              // tw(l)*tw(192)
    float2 tw1[2];
    tw1[0] = make_float2(c2, s2);
    tw1[1] = make_float2(s2, -c2);                          // tw(2l)*tw(128)
    const float2 w2 = make_float2(c2 * c2 - s2 * s2, 2.f * c2 * s2);  // tw(4l)
    float2 wst[5];
    wst[0] = make_float2(cw0, sw0);
    wst[1] = make_float2(cw1, sw1);
    wst[2] = make_float2(cw2, sw2);
    {
        int j2 = l & 3;
        float cc3 = (j2 == 0) ? 1.f : (j2 == 1) ? R2 : (j2 == 2) ? 0.f : -R2;
        float ss3 = (j2 == 0) ? 0.f : (j2 == 2) ? -1.f : -R2;
        wst[3] = make_float2(cc3, ss3);                     // tw(64(l&3))
    }
    wst[4] = (l & 1) ? make_float2(0.f, -1.f) : make_float2(1.f, 0.f);  // tw(128(l&1))

    const float* xa = x + (size_t)b0 * NL;
    const float* xb = xa + NL;
    float xr[8], xi[8];
#pragma unroll
    for (int k = 0; k < 8; k++) { xr[k] = xa[k * 64 + l]; xi[k] = xb[k * 64 + l]; }
    const float last_a = __shfl(xr[7], 63);
    const float last_b = __shfl(xi[7], 63);

    if (xb16) {   // K-permuted bf16 copy: lane stores its 8 values contiguously
        unsigned pa_[4], pb_[4];
#pragma unroll
        for (int j = 0; j < 4; j++) {
            asm("v_cvt_pk_bf16_f32 %0, %1, %2" : "=v"(pa_[j]) : "v"(xr[2 * j]), "v"(xr[2 * j + 1]));
            asm("v_cvt_pk_bf16_f32 %0, %1, %2" : "=v"(pb_[j]) : "v"(xi[2 * j]), "v"(xi[2 * j + 1]));
        }
        *(uint4*)(xb16 + (size_t)b0 * NL + l * 8)       = *(uint4*)pa_;
        *(uint4*)(xb16 + (size_t)(b0 + 1) * NL + l * 8) = *(uint4*)pb_;
    }

    // ---- DIF FFT (complex), natural in, bit-reversed out ----
#pragma unroll
    for (int k = 0; k < 4; k++) {                       // stage 0: half=256
        float2 w = tw0[k];
        float ur = xr[k], ui = xi[k], vr = xr[k + 4], vi = xi[k + 4];
        xr[k] = ur + vr; xi[k] = ui + vi;
        float dr = ur - vr, di = ui - vi;
        xr[k + 4] = dr * w.x - di * w.y; xi[k + 4] = dr * w.y + di * w.x;
    }
    {                                                   // stage 1: half=128
        const int kk[4] = {0, 1, 4, 5};
#pragma unroll
        for (int g2 = 0; g2 < 4; g2++) {
            int k = kk[g2];
            float2 w = tw1[k & 1];
            float ur = xr[k], ui = xi[k], vr = xr[k + 2], vi = xi[k + 2];
            xr[k] = ur + vr; xi[k] = ui + vi;
            float dr = ur - vr, di = ui - vi;
            xr[k + 2] = dr * w.x - di * w.y; xi[k + 2] = dr * w.y + di * w.x;
        }
    }
    {                                                   // stage 2: half=64
#pragma unroll
        for (int k = 0; k < 8; k += 2) {
            float ur = xr[k], ui = xi[k], vr = xr[k + 1], vi = xi[k + 1];
            xr[k] = ur + vr; xi[k] = ui + vi;
            float dr = ur - vr, di = ui - vi;
            xr[k + 1] = dr * w2.x - di * w2.y; xi[k + 1] = dr * w2.y + di * w2.x;
        }
    }
#pragma unroll
    for (int st = 3; st < 8; st++) {                    // stages 3..7 cross-lane
        const int half = 256 >> st;
        const float2 w = wst[st - 3];
        const bool up = (l & half) != 0;
        const float sg = up ? -1.f : 1.f;
        const float cc = up ? w.x : 1.f;
        const float ss = up ? w.y : 0.f;
#pragma unroll
        for (int k = 0; k < 8; k++) {
            float pr = __shfl_xor(xr[k], half);
            float pi = __shfl_xor(xi[k], half);
            float tr = fmaf(sg, xr[k], pr);
            float ti = fmaf(sg, xi[k], pi);
            xr[k] = tr * cc - ti * ss;
            xi[k] = tr * ss + ti * cc;
        }
    }
    {                                                   // stage 8: half=1, w=(1,0)
        const float sg = (l & 1) ? -1.f : 1.f;
#pragma unroll
        for (int k = 0; k < 8; k++) {
            float pr = __shfl_xor(xr[k], 1);
            float pi = __shfl_xor(xi[k], 1);
            xr[k] = fmaf(sg, xr[k], pr);
            xi[k] = fmaf(sg, xi[k], pi);
        }
    }

#pragma unroll
    for (int k = 0; k < 8; k++) {
        int i = k * 64 + l;
        s_z[wv][i + (i >> 3)] = make_float2(xr[k], xi[k]);
    }
    // s_z[wv] is wave-private: no barrier needed.

    // conjugate-symmetry split: lane l owns bins f = 4l..4l+3
    float Ia[4], Ib[4];
    float psa = 0.f, psb = 0.f;
#pragma unroll
    for (int j = 0; j < 4; j++) {
        int f = (l << 2) | j;
        int i1_ = (int)(__brev((unsigned)f) >> 23);
        int i2_ = (int)(__brev((unsigned)((512 - f) & 511)) >> 23);
        float2 z1 = s_z[wv][i1_ + (i1_ >> 3)];
        float2 z2 = s_z[wv][i2_ + (i2_ >> 3)];
        float pr_ = z1.x + z2.x, qm = z1.y - z2.y;
        float qp = z1.y + z2.y, pm = z1.x - z2.x;
        float va = pr_ * pr_ + qm * qm;
        float vb = qp * qp + pm * pm;
        if (f == 0) { va = 0.f; vb = 0.f; }   // centering only affects bin 0
        Ia[j] = va; Ib[j] = vb;
        psa += va; psb += vb;
    }
#pragma unroll
    for (int m = 1; m < 64; m <<= 1) {
        psa += __shfl_xor(psa, m); psb += __shfl_xor(psb, m);
    }
    const float psa_raw = psa, psb_raw = psb;
    if (psa == 0.f) psa = 1.f;
    if (psb == 0.f) psb = 1.f;
    const float inv_a = 1.f / psa, inv_b = 1.f / psb;

    const float2 Z0   = s_z[wv][0];
    const float2 Z256 = s_z[wv][1];

    float* wI = s_Iv + wv * 1152;
    const int io = (l << 2) + ((l >> 4) << 2);
    *(float4*)(wI + io)       = make_float4(Ia[0], Ia[1], Ia[2], Ia[3]);
    *(float4*)(wI + 272 + io) = make_float4(Ib[0], Ib[1], Ib[2], Ib[3]);

    // gate matmul: lane (e = l&15, cq = l>>4) sums quarter cq for expert e
    const int e16 = l & 15, cq = l >> 4;
    const float bgv = bgT[e16];
    float accA = 0.f, accB = 0.f;
    const float* rA = wI + cq * 68;
    const float* rB = rA + 272;
#pragma unroll 4
    for (int jj = 0; jj < 16; jj++) {
        float4 ia = *(const float4*)(rA + 4 * jj);
        float4 ib = *(const float4*)(rB + 4 * jj);
        float4 w = WgE4[(cq * 16 + jj) * 16 + e16];
        accA += ia.x * w.x + ia.y * w.y + ia.z * w.z + ia.w * w.w;
        accB += ib.x * w.x + ib.y * w.y + ib.z * w.z + ib.w * w.w;
    }
    accA += __shfl_xor(accA, 16); accA += __shfl_xor(accA, 32);
    accB += __shfl_xor(accB, 16); accB += __shfl_xor(accB, 32);

    float v = ((l & 16) ? accB * inv_b : accA * inv_a) + bgv;

    // parallel top-3 within 16-lane group, first-index tie-break
    float b0v = v; int b0i = e16;
#pragma unroll
    for (int m = 1; m < 16; m <<= 1) {
        float ov = __shfl_xor(b0v, m); int oi = __shfl_xor(b0i, m);
        if (ov > b0v || (ov == b0v && oi < b0i)) { b0v = ov; b0i = oi; }
    }
    float v1 = (e16 == b0i) ? -1e30f : v;
    float b1v = v1; int b1i = e16;
#pragma unroll
    for (int m = 1; m < 16; m <<= 1) {
        float ov = __shfl_xor(b1v, m); int oi = __shfl_xor(b1i, m);
        if (ov > b1v || (ov == b1v && oi < b1i)) { b1v = ov; b1i = oi; }
    }
    float v2 = (e16 == b1i) ? -1e30f : v1;
    float b2v = v2;
#pragma unroll
    for (int m = 1; m < 16; m <<= 1) {
        float ov = __shfl_xor(b2v, m);
        b2v = fmaxf(b2v, ov);
    }

    if (l == 0 || l == 16) {
        const int r = l >> 4;
        const int b = b0 + r;
        const float mu = (r ? Z0.y : Z0.x) * (1.f / 512.f);
        const float Jv = r ? Z256.y : Z256.x;
        const float ps = r ? psb_raw : psa_raw;
        const float sd = sqrtf((0.5f * ps + Jv * Jv) * (1.f / 262144.f) + 1e-5f);
        const float last = r ? last_b : last_a;
        const float w0 = 1.f / (1.f + expf(b1v - b0v));
        const int pid = b0i * 16 + b1i;
        const int lo = atomicAdd(&pcnt[pid << 4], 1);
        rec[b] = (pid << 24) | lo;
        hdr[b] = make_float4(mu, sd, last, w0);
        if (b1v - b2v < TAU) {
            int pos = atomicAdd(flagcnt, 1);
            flaglist[pos] = b;
        }
    }
}

// f64 phasor-DFT refinement for flagged rows. Reclass = append new (pid,lo)
// and record old packed slot as a hole (patched to -1 in k_scatter).
__global__ __launch_bounds__(256) void k_refine(
    const float* __restrict__ x, const double2* __restrict__ twd,
    const float* __restrict__ Wg, const float* __restrict__ bg,
    int* __restrict__ rec, float4* __restrict__ hdr,
    const int* __restrict__ flaglist, const int* __restrict__ flagcnt,
    int* __restrict__ pcnt, int* __restrict__ holes, int* __restrict__ holecnt)
{
    __shared__ double s_x[512];
    __shared__ double s_I[256];
    __shared__ double s_red[16];
    __shared__ double s_g[16];
    const int nf = *flagcnt;
    const int t = threadIdx.x;
    const int wid = t >> 6, lane = t & 63;
    for (int fi = blockIdx.x; fi < nf; fi += gridDim.x) {
        const int b = flaglist[fi];
        const float* xp = x + (size_t)b * NL;
        double v0 = (double)xp[t], v1 = (double)xp[t + 256];
        double lsum = v0 + v1;
        for (int m = 1; m < 64; m <<= 1) lsum += __shfl_xor(lsum, m);
        if (lane == 0) s_red[wid] = lsum;
        __syncthreads();
        double mu = (s_red[0] + s_red[1] + s_red[2] + s_red[3]) * (1.0 / 512.0);
        s_x[t] = v0 - mu; s_x[t + 256] = v1 - mu;
        __syncthreads();
        double2 w = twd[t];
        double pr = 1.0, pi = 0.0, cr = 0.0, ci = 0.0;
        for (int n = 0; n < 512; n++) {
            double xv = s_x[n];
            cr += xv * pr; ci += xv * pi;
            double t2 = pr * w.x - pi * w.y;
            pi = pr * w.y + pi * w.x;
            pr = t2;
        }
        double I = cr * cr + ci * ci;
        s_I[t] = I;
        double ls = I;
        for (int m = 1; m < 64; m <<= 1) ls += __shfl_xor(ls, m);
        if (lane == 0) s_red[8 + wid] = ls;
        __syncthreads();
        double stot = s_red[8] + s_red[9] + s_red[10] + s_red[11];
        if (stot == 0.0) stot = 1.0;
        if (t < 16) {
            double acc = 0.0;
            const float* wrow = Wg + t * NF;
            for (int f = 0; f < NF; f++) acc += s_I[f] * (double)wrow[f];
            s_g[t] = (acc / stot + (double)bg[t]) * (1.0 / 0.07);
        }
        __syncthreads();
        if (t == 0) {
            double c0 = -1e300, c1 = -1e300; int j0 = 0, j1 = 0;
            for (int i = 0; i < 16; i++) {
                double v = s_g[i];
                if (v > c0) { c1 = c0; j1 = j0; c0 = v; j0 = i; }
                else if (v > c1) { c1 = v; j1 = i; }
            }
            double e1 = exp(c1 - c0);
            float w0f = (float)(1.0 / (1.0 + e1));
            int newpid = j0 * 16 + j1;
            int oldrec = rec[b];
            int oldpid = (int)(((unsigned)oldrec) >> 24);
            if (newpid == oldpid) {
                ((float*)(hdr + b))[3] = w0f;
            } else {
                int pos = atomicAdd(holecnt, 1);
                if (pos < 4096) {   // overflow: keep f32 selection (same as TAU-miss)
                    int nlo = atomicAdd(&pcnt[newpid << 4], 1);
                    rec[b] = (newpid << 24) | nlo;
                    holes[pos] = oldrec;
                    ((float*)(hdr + b))[3] = w0f;
                }
            }
        }
        __syncthreads();
    }
}

// Scan pair counts -> pbase AND flat chunk descriptors (load balance).
__global__ __launch_bounds__(256) void k_scan(
    const int* __restrict__ pcnt, int* __restrict__ pbase,
    int* __restrict__ desc, int* __restrict__ nchk)
{
    __shared__ int s[256], c[256];
    const int t = threadIdx.x;
    const int n = pcnt[t << 4];
    s[t] = n;
    c[t] = (n + 63) >> 6;
    __syncthreads();
    for (int off = 1; off < 256; off <<= 1) {
        int v1 = (t >= off) ? s[t - off] : 0;
        int v2 = (t >= off) ? c[t - off] : 0;
        __syncthreads();
        s[t] += v1; c[t] += v2;
        __syncthreads();
    }
    int excl = t ? s[t - 1] : 0;
    int cexcl = t ? c[t - 1] : 0;
    pbase[t] = excl;
    int myc = (n + 63) >> 6;
    for (int j = 0; j < myc; j++) desc[cexcl + j] = (t << 16) | j;
    if (t == 255) *nchk = cexcl + myc;
}

// Atomic-free scatter: slot comes from packed rec. Block 0 patches holes.
__global__ __launch_bounds__(256) void k_scatter(
    const int* __restrict__ rec, const int* __restrict__ pbase,
    int* __restrict__ ridx,
    const int* __restrict__ holes, const int* __restrict__ holecnt)
{
    const int t = threadIdx.x;
    const int b = blockIdx.x * 256 + t;
    unsigned v = (unsigned)rec[b];
    ridx[pbase[v >> 24] + (v & 0xFFFFFF)] = b;
    if (blockIdx.x == 0) {
        int nh = *holecnt; if (nh > 4096) nh = 4096;
        for (int h = t; h < nh; h += 256) {
            unsigned hv = (unsigned)holes[h];
            ridx[pbase[hv >> 24] + (hv & 0xFFFFFF)] = -1;
        }
    }
}

// Pair-bucket MFMA GEMM with register prefetch (T14 async-stage split).
// XB=1: A read as bf16 from xb16 (K-permuted, matching Wrb).
// Hole slots (ridx = -1) are skipped; prefetch falls back to row 0.
template<int XB>
__global__ __launch_bounds__(256) void k_gemm(
    const float* __restrict__ x, const unsigned short* __restrict__ xb16,
    const unsigned short* __restrict__ Wrb,
    const float* __restrict__ br, const float* __restrict__ Ssum,
    const float4* __restrict__ hdr, float* __restrict__ out,
    const int* __restrict__ pcnt, const int* __restrict__ pbase,
    const int* __restrict__ ridx,
    const int* __restrict__ desc, const int* __restrict__ nchk)
{
    __shared__ __align__(16) unsigned short sA[64 * 72];      // [r][k]
    __shared__ __align__(16) unsigned short sB[2][96 * 72];   // [ex][p][k]
    __shared__ int    s_idx[64];
    __shared__ float4 s_hdr[64];
    __shared__ float  s_br[2][96], s_S[2][96];
    if ((int)blockIdx.x >= *nchk) return;
    const int d = desc[blockIdx.x];
    const int pid = d >> 16, cc = d & 0xffff;
    const int n = pcnt[pid << 4];
    const int base = pbase[pid];
    const int i0 = pid >> 4, i1 = pid & 15;
    const int t = threadIdx.x;
    const int lane = t & 63, wv = t >> 6;
    const int quad = lane >> 4, l16 = lane & 15;
    const int ar = t >> 2, asub = t & 3;
    if (t < 96) {
        s_br[0][t] = (i0 < NEL) ? br[i0 * NP + t] : 0.f;
        s_S [0][t] = (i0 < NEL) ? Ssum[i0 * NP + t] : 0.f;
        s_br[1][t] = (i1 < NEL) ? br[i1 * NP + t] : 0.f;
        s_S [1][t] = (i1 < NEL) ? Ssum[i1 * NP + t] : 0.f;
    }
    if (t < 64) {
        int g = cc * 64 + t;
        bool vld = g < n;
        int row = vld ? ridx[base + g] : -1;
        s_idx[t] = row;
        s_hdr[t] = (row >= 0) ? hdr[row] : make_float4(0.f, 0.f, 0.f, 0.f);
    }
    __syncthreads();

    f32x4 acc[2][6];
#pragma unroll
    for (int ex = 0; ex < 2; ex++)
#pragma unroll
        for (int j = 0; j < 6; j++) acc[ex][j] = (f32x4){0.f, 0.f, 0.f, 0.f};

    int rr = s_idx[ar]; if (rr < 0) rr = 0;

    unsigned boff[6];
    unsigned short* bdst[6];
    const unsigned short* wb[2];
    wb[0] = Wrb + (size_t)i0 * NP * NL;
    wb[1] = Wrb + (size_t)i1 * NP * NL;
    int bex[6];
#pragma unroll
    for (int it = 0; it < 6; it++) {
        int ex = (it >= 3);
        int fl = t + (it - 3 * ex) * 256;
        int p = fl >> 3, kg = fl & 7;
        bex[it] = ex;
        boff[it] = (unsigned)(p * NL + kg * 8);
        bdst[it] = &sB[ex][p * 72 + kg * 8];
    }
    unsigned short* adst = sA + ar * 72 + asub * 16;

    const unsigned short* xrow16 = xb16 + (size_t)rr * NL + asub * 16;
    const float* xrowf = x + (size_t)rr * NL + asub * 16;

    bf16x8 aR[2]; float4 fA[4]; bf16x8 bR[6];

    if constexpr (XB) {
        aR[0] = *(const bf16x8*)(xrow16);
        aR[1] = *(const bf16x8*)(xrow16 + 8);
    } else {
#pragma unroll
        for (int i = 0; i < 4; i++) fA[i] = ((const float4*)xrowf)[i];
    }
#pragma unroll
    for (int it = 0; it < 6; it++) bR[it] = *(const bf16x8*)(wb[bex[it]] + boff[it]);

    for (int kb = 0; kb < NL; kb += 64) {
        if constexpr (XB) {
            *(bf16x8*)adst       = aR[0];
            *(bf16x8*)(adst + 8) = aR[1];
        } else {
            unsigned short tmp[16];
#pragma unroll
            for (int i = 0; i < 4; i++) {
                float4 v = fA[i];
                tmp[i * 4 + 0] = f2bf(v.x); tmp[i * 4 + 1] = f2bf(v.y);
                tmp[i * 4 + 2] = f2bf(v.z); tmp[i * 4 + 3] = f2bf(v.w);
            }
            *(bf16x8*)adst       = *(bf16x8*)tmp;
            *(bf16x8*)(adst + 8) = *(bf16x8*)(tmp + 8);
        }
#pragma unroll
        for (int it = 0; it < 6; it++) *(bf16x8*)bdst[it] = bR[it];
        __syncthreads();

        const int kn = kb + 64;
        if (kn < NL) {
            if constexpr (XB) {
                aR[0] = *(const bf16x8*)(xrow16 + kn);
                aR[1] = *(const bf16x8*)(xrow16 + kn + 8);
            } else {
#pragma unroll
                for (int i = 0; i < 4; i++) fA[i] = ((const float4*)(xrowf + kn))[i];
            }
#pragma unroll
            for (int it = 0; it < 6; it++)
                bR[it] = *(const bf16x8*)(wb[bex[it]] + boff[it] + kn);
        }

#pragma unroll
        for (int ks = 0; ks < 2; ks++) {
            bf16x8 af = *(const bf16x8*)(sA + (wv * 16 + l16) * 72 + ks * 32 + quad * 8);
#pragma unroll
            for (int ex = 0; ex < 2; ex++)
#pragma unroll
                for (int nt = 0; nt < 6; nt++) {
                    bf16x8 bf = *(const bf16x8*)(&sB[ex][(nt * 16 + l16) * 72 + ks * 32 + quad * 8]);
                    acc[ex][nt] = __builtin_amdgcn_mfma_f32_16x16x32_bf16(af, bf, acc[ex][nt], 0, 0, 0);
                }
        }
        __syncthreads();
    }
#pragma unroll
    for (int i = 0; i < 4; i++) {
        int rloc = wv * 16 + quad * 4 + i;
        int row = s_idx[rloc];
        if (row >= 0) {
            float4 h = s_hdr[rloc];
            float mu = h.x, sd = h.y, last = h.z, w0 = h.w, w1 = 1.f - w0;
            float* orow = out + (size_t)row * NP;
#pragma unroll
            for (int nt = 0; nt < 6; nt++) {
                int p = nt * 16 + l16;
                float v0 = (i0 < NEL) ? (mu + s_br[0][p] * sd - mu * s_S[0][p] + acc[0][nt][i])
                                      : (i0 == NEL ? mu : last);
                float v1 = (i1 < NEL) ? (mu + s_br[1][p] * sd - mu * s_S[1][p] + acc[1][nt][i])
                                      : (i1 == NEL ? mu : last);
                orow[p] = w0 * v0 + w1 * v1;
            }
        }
    }
}

extern "C" void kernel_launch(void* const* d_in, const int* in_sizes, int n_in,
                              void* d_out, int out_size, void* d_ws, size_t ws_size,
                              hipStream_t stream)
{
    const float* x  = (const float*)d_in[0];
    const float* Wg = (const float*)d_in[1];
    const float* bg = (const float*)d_in[2];
    const float* Wr = (const float*)d_in[3];
    const float* br = (const float*)d_in[4];
    float* out = (float*)d_out;
    char* ws = (char*)d_ws;

    int*     pcnt     = (int*)(ws + WS_PCNT);
    int*     holes    = (int*)(ws + WS_HOLES);
    int*     pbase    = (int*)(ws + WS_PBASE);
    int*     flagcnt  = (int*)(ws + WS_FLAGCNT);
    int*     nchk     = (int*)(ws + WS_NCHK);
    int*     holecnt  = (int*)(ws + WS_HOLECNT);
    int*     flaglist = (int*)(ws + WS_FLAG);
    float*   Ssum     = (float*)(ws + WS_SSUM);
    float*   WgE      = (float*)(ws + WS_WGT);
    float*   bgT      = (float*)(ws + WS_BGT);
    double2* twd      = (double2*)(ws + WS_TWD);
    int*     rec      = (int*)(ws + WS_REC);
    float4*  hdr      = (float4*)(ws + WS_HDR);
    int*     ridx     = (int*)(ws + WS_RIDX);
    unsigned short* Wrb = (unsigned short*)(ws + WS_WRB);
    int*     desc     = (int*)(ws + WS_DESC);

    const size_t xb_bytes = (size_t)NB_B * NL * 2;
    const int use_xb = (ws_size >= (size_t)WS_XB16 + xb_bytes);
    unsigned short* xb16 = use_xb ? (unsigned short*)(ws + WS_XB16) : (unsigned short*)0;

    k_prep<<<dim3(768), dim3(256), 0, stream>>>(Wg, bg, Wr, Ssum, WgE, bgT, twd,
                                                pcnt, flagcnt, holecnt,
                                                (ushort4*)Wrb, use_xb);
    k_gate<<<dim3(NB_B / 8), dim3(256), 0, stream>>>(x, (const float4*)WgE, bgT,
                                                     rec, hdr, flaglist, flagcnt, pcnt, xb16);
    k_refine<<<dim3(512), dim3(256), 0, stream>>>(x, twd, Wg, bg, rec, hdr,
                                                  flaglist, flagcnt, pcnt, holes, holecnt);
    k_scan<<<dim3(1), dim3(256), 0, stream>>>(pcnt, pbase, desc, nchk);
    k_scatter<<<dim3(NB_B / 256), dim3(256), 0, stream>>>(rec, pbase, ridx, holes, holecnt);
    if (use_xb)
        k_gemm<1><<<dim3(MAXCHK), dim3(256), 0, stream>>>(x, xb16, Wrb, br, Ssum, hdr, out,
                                                          pcnt, pbase, ridx, desc, nchk);
    else
        k_gemm<0><<<dim3(MAXCHK), dim3(256), 0, stream>>>(x, xb16, Wrb, br, Ssum, hdr, out,
                                                          pcnt, pbase, ridx, desc, nchk);
}